// Round 15
// baseline (147.547 us; speedup 1.0000x reference)
//
#include <hip/hip_runtime.h>
#include <stdint.h>

typedef short short8 __attribute__((ext_vector_type(8)));
typedef float f32x4 __attribute__((ext_vector_type(4)));
typedef float f32x16 __attribute__((ext_vector_type(16)));
typedef unsigned short u16;

#define N_TOT 32768
#define EV 4096

__device__ __forceinline__ u16 f2bf(float f){
  unsigned int x = __float_as_uint(f);
  x += 0x7FFFu + ((x >> 16) & 1u);
  return (u16)(x >> 16);
}
__device__ __forceinline__ unsigned umin_(unsigned a, unsigned b){ return a<b?a:b; }

// ---------------- Kernel A: fused stage+s (single x pass), h (bf16 MFMA); +kW fold ---
__global__ __launch_bounds__(256, 3) void kA(
    const float* __restrict__ x, const float* __restrict__ Ws,
    const float* __restrict__ bs, const float* __restrict__ Wh,
    const float* __restrict__ bh, const float* __restrict__ Wo,
    float* __restrict__ sOut, uint4* __restrict__ sfrag,
    unsigned short* __restrict__ hOut, unsigned int* __restrict__ WoT2)
{
  if (blockIdx.x >= N_TOT/64){                 // folded kW: Wo [320][256] f32 -> WoT [256][320] bf16
    const int kb = (blockIdx.x - N_TOT/64) * 32;
    const int c = threadIdx.x;
    unsigned int prev = 0;
    for (int k=0;k<32;++k){
      float v = Wo[(size_t)(kb+k)*256 + c];
      u16 h = f2bf(v);
      if (k & 1) WoT2[(size_t)c*160 + ((kb+k)>>1)] = prev | ((unsigned)h<<16);
      else       prev = (unsigned)h;
    }
    return;
  }
  __shared__ u16 xh[64*264];     // bf16 x tile [row][k], stride 264 u16 (33.8KB)
  __shared__ u16 whT[32*264];    // bf16 Wh^T [col][k], stride 264 (16.9KB)
  const int t = threadIdx.x;
  const int wv = t >> 6, l = t & 63;
  const int r0 = blockIdx.x * 64;

  // stage whT: Wh [256][32] f32 -> whT[col][k] bf16
  #pragma unroll
  for (int i=0;i<32;++i){
    int k = i*8 + (t>>5);
    int col = t & 31;
    whT[col*264 + k] = f2bf(Wh[(size_t)k*32 + col]);
  }

  // fused: stage xh (bf16) + s fp32 partials, ONE pass over x.
  {
    const int row = t >> 2, c40 = t & 3;
    const float4* xr = (const float4*)(x + (size_t)(r0+row)*256);
    const float4* wsr = (const float4*)Ws;   // Ws[k][0..3]
    float a0=0.f,a1=0.f,a2=0.f,a3=0.f;
    #pragma unroll
    for (int i=0;i<16;++i){
      int c4 = c40 + i*4;
      float4 xv = xr[c4];
      unsigned p0,p1;
      asm("v_cvt_pk_bf16_f32 %0, %1, %2" : "=v"(p0) : "v"(xv.x), "v"(xv.y));
      asm("v_cvt_pk_bf16_f32 %0, %1, %2" : "=v"(p1) : "v"(xv.z), "v"(xv.w));
      uint2 pk = {p0, p1};
      *(uint2*)&xh[row*264 + c4*4] = pk;
      float4 w0 = wsr[c4*4+0], w1 = wsr[c4*4+1], w2 = wsr[c4*4+2], w3 = wsr[c4*4+3];
      a0 += xv.x*w0.x + xv.y*w1.x + xv.z*w2.x + xv.w*w3.x;
      a1 += xv.x*w0.y + xv.y*w1.y + xv.z*w2.y + xv.w*w3.y;
      a2 += xv.x*w0.z + xv.y*w1.z + xv.z*w2.z + xv.w*w3.z;
      a3 += xv.x*w0.w + xv.y*w1.w + xv.z*w2.w + xv.w*w3.w;
    }
    a0 += __shfl_xor(a0,1); a0 += __shfl_xor(a0,2);
    a1 += __shfl_xor(a1,1); a1 += __shfl_xor(a1,2);
    a2 += __shfl_xor(a2,1); a2 += __shfl_xor(a2,2);
    a3 += __shfl_xor(a3,1); a3 += __shfl_xor(a3,2);
    if (c40 == 0){
      float4 sv = { a0+bs[0], a1+bs[1], a2+bs[2], a3+bs[3] };
      ((float4*)sOut)[r0 + row] = sv;
      // A-side (point) fragment: k0-7 = [hi4,hi4]; k8-15 = [lo4, nh, nl, 1, 1]
      u16 h0=f2bf(sv.x), h1=f2bf(sv.y), h2=f2bf(sv.z), h3=f2bf(sv.w);
      float e0 = sv.x - __uint_as_float((unsigned)h0<<16);
      float e1 = sv.y - __uint_as_float((unsigned)h1<<16);
      float e2 = sv.z - __uint_as_float((unsigned)h2<<16);
      float e3 = sv.w - __uint_as_float((unsigned)h3<<16);
      u16 l0=f2bf(e0), l1=f2bf(e1), l2=f2bf(e2), l3=f2bf(e3);
      float n = sv.x*sv.x + sv.y*sv.y + sv.z*sv.z + sv.w*sv.w;
      u16 nh = f2bf(n);
      u16 nl = f2bf(n - __uint_as_float((unsigned)nh<<16));
      uint4 w0, w1;
      w0.x = (unsigned)h0 | ((unsigned)h1<<16);
      w0.y = (unsigned)h2 | ((unsigned)h3<<16);
      w0.z = w0.x; w0.w = w0.y;
      w1.x = (unsigned)l0 | ((unsigned)l1<<16);
      w1.y = (unsigned)l2 | ((unsigned)l3<<16);
      w1.z = (unsigned)nh | ((unsigned)nl<<16);
      w1.w = 0x3F803F80u;                       // 1.0, 1.0 (pairs with B's si2 hi/lo)
      sfrag[(size_t)(r0+row)*2 + 0] = w0;
      sfrag[(size_t)(r0+row)*2 + 1] = w1;
    }
  }
  __syncthreads();

  // h = x @ Wh via MFMA: wave wv -> rows 16wv..16wv+15; 2 col-tiles of 16.
  {
    const int lq = l & 15, g = l >> 4;
    const f32x4 zero = {0.f,0.f,0.f,0.f};
    f32x4 h0 = zero, h1 = zero;
    #pragma unroll
    for (int ks=0; ks<8; ++ks){
      short8 a  = *(const short8*)&xh[(wv*16+lq)*264 + ks*32 + g*8];
      short8 b0 = *(const short8*)&whT[lq*264       + ks*32 + g*8];
      short8 b1 = *(const short8*)&whT[(16+lq)*264  + ks*32 + g*8];
      h0 = __builtin_amdgcn_mfma_f32_16x16x32_bf16(a, b0, h0, 0,0,0);
      h1 = __builtin_amdgcn_mfma_f32_16x16x32_bf16(a, b1, h1, 0,0,0);
    }
    float bv0 = bh[lq], bv1 = bh[16+lq];
    #pragma unroll
    for (int rg=0; rg<4; ++rg){
      int rowg = r0 + wv*16 + g*4 + rg;
      hOut[(size_t)rowg*32 + lq]      = f2bf(h0[rg] + bv0);
      hOut[(size_t)rowg*32 + 16 + lq] = f2bf(h1[rg] + bv1);
    }
  }
}

// ---------------- Kernel B: 32x32x16-MFMA radix-select kNN, full-sample tau ----------
// 1024 blocks (= 4/CU); block: 32 queries, 4 waves each scanning a 1024-pt quarter
// in 32-pt tiles (mfma_f32_32x32x16_bf16, K=16).
// Pass 1 (ALL 32 tiles/wave; 4 waves together = full event): exact packed 128-bin
//   quarter-octave histogram -> tight tau (survivors ~= 16 + |threshold bin|).
// Pass 2 (32 tiles): signed-compare survivor push to slist; scnt counts ALL.
// Final (ALL 4 waves): 8 helper lanes/query (wave w: queries (w&1)*16.., strides
//   (w>>1)*4+g); exact fp32 d^2 (overflow -> full scan), bubble, xor16/32 in-wave
//   merge + cross-wave-pair MERGE16 via mrg; waves 0/1 aggregate.
#define BUBBLE16(v)                                              \
  { _Pragma("unroll")                                            \
    for (int k=0;k<16;++k){                                      \
      unsigned int mn = (v) < bp[k] ? (v) : bp[k];               \
      unsigned int mx = (v) < bp[k] ? bp[k] : (v);               \
      bp[k] = mn; (v) = mx;                                      \
    } }

#define MERGE16(OT)                                              \
  { unsigned int c[16];                                          \
    _Pragma("unroll")                                            \
    for (int k=0;k<16;++k){ unsigned int b2 = (OT)[15-k];        \
      c[k] = bp[k] < b2 ? bp[k] : b2; }                          \
    _Pragma("unroll")                                            \
    for (int d=8; d>=1; d>>=1){                                  \
      _Pragma("unroll")                                          \
      for (int i=0;i<16;++i){                                    \
        if ((i & d) == 0){                                       \
          unsigned int lo = c[i] < c[i+d] ? c[i] : c[i+d];       \
          unsigned int hi = c[i] < c[i+d] ? c[i+d] : c[i];       \
          c[i] = lo; c[i+d] = hi;                                \
        }                                                        \
      }                                                          \
    }                                                            \
    _Pragma("unroll")                                            \
    for (int k=0;k<16;++k) bp[k] = c[k]; }

#define SCAP 448
#define BIN_LO 440u   // 110*4: window start (exp 110 -> d2 ~ 4e-6)

#define P1BODY(F, TL)                                            \
  { union { uint4 q; short8 v; } au; au.q = (F);                 \
    (F) = fw[(size_t)((TL)+4)*64 + a64];                         \
    f32x16 acc = __builtin_amdgcn_mfma_f32_32x32x16_bf16(au.v, bq, zacc, 0,0,0); \
    _Pragma("unroll")                                            \
    for (int rg=0; rg<16; ++rg){                                 \
      unsigned u = __float_as_uint(fmaxf(acc[rg],0.f));          \
      unsigned q21 = u >> 21;                                    \
      unsigned b = (q21 < BIN_LO) ? 0u : umin_(q21 - BIN_LO, 127u); \
      atomicAdd(&hist[hbase + (b>>1)], (b&1u) ? 0x10000u : 1u);  \
    } }

#define P2BODY(F, TL)                                            \
  { union { uint4 q; short8 v; } au; au.q = (F);                 \
    (F) = fw[(size_t)((TL)+4)*64 + a64];                         \
    f32x16 acc = __builtin_amdgcn_mfma_f32_32x32x16_bf16(au.v, bq, zacc, 0,0,0); \
    const int jb2 = jb + (TL)*32;                                \
    _Pragma("unroll")                                            \
    for (int rg=0; rg<16; ++rg){                                 \
      int u = (int)__float_as_uint(acc[rg]);                     \
      if (u < tauS){                                             \
        int j = jb2 + (rg&3) + 8*(rg>>2);                        \
        unsigned idx = atomicAdd(&scnt[q32], 1u);                \
        if (idx < (unsigned)SCAP) slist[q32*SCAP + idx] = (u16)j; \
      }                                                          \
    } }

__global__ __launch_bounds__(256, 4) void kB(
    const float* __restrict__ sIn, const uint4* __restrict__ sfrag,
    const unsigned short* __restrict__ hIn, unsigned short* __restrict__ Umini)
{
  __shared__ unsigned int hist[32*65];     // 128 bins packed 2-per-word, stride 65 (8.3KB)
  __shared__ u16 slist[32*SCAP];           // per-query survivor indices (28KB)
  __shared__ unsigned int scnt[32];
  __shared__ unsigned int tauL[32];
  __shared__ unsigned int mrg[32][17];     // cross-wave-pair merge lists (2.2KB)
  const int t = threadIdx.x;
  const int wv = t >> 6, l = t & 63;
  const int e = blockIdx.x >> 7;           // 128 blocks/event
  const int qblk = (blockIdx.x & 127) * 32;
  const int q32 = l & 31, hi = l >> 5;
  const int qloc = qblk + q32;

  const float4* sg = (const float4*)sIn;
  const float4 sq = sg[(size_t)e*EV + qloc];
  const float si2 = sq.x*sq.x + sq.y*sq.y + sq.z*sq.z + sq.w*sq.w;

  // B (query col q32) fragment: hi=0 -> k0-7 [-2s_hi4 | -2s_lo4]; hi=1 -> k8-15 [-2s_hi4 | 1,1,sh,sl]
  union BU { u16 u[8]; short8 v; } bu;
  {
    float tx=-2.f*sq.x, ty=-2.f*sq.y, tz=-2.f*sq.z, tw=-2.f*sq.w;
    u16 h0=f2bf(tx), h1=f2bf(ty), h2=f2bf(tz), h3=f2bf(tw);
    bu.u[0]=h0; bu.u[1]=h1; bu.u[2]=h2; bu.u[3]=h3;
    if (hi==0){
      float e0 = tx - __uint_as_float((unsigned)h0<<16);
      float e1 = ty - __uint_as_float((unsigned)h1<<16);
      float e2 = tz - __uint_as_float((unsigned)h2<<16);
      float e3 = tw - __uint_as_float((unsigned)h3<<16);
      bu.u[4]=f2bf(e0); bu.u[5]=f2bf(e1); bu.u[6]=f2bf(e2); bu.u[7]=f2bf(e3);
    } else {
      u16 sh = f2bf(si2);
      u16 sl = f2bf(si2 - __uint_as_float((unsigned)sh<<16));
      bu.u[4]=0x3F80; bu.u[5]=0x3F80; bu.u[6]=sh; bu.u[7]=sl;
    }
  }
  const short8 bq = bu.v;

  // zero histogram + counters
  for (int i=t; i<32*65; i+=256) hist[i]=0;
  if (t < 32) scnt[t] = 0;
  __syncthreads();

  const f32x16 zacc = {0.f,0.f,0.f,0.f,0.f,0.f,0.f,0.f,0.f,0.f,0.f,0.f,0.f,0.f,0.f,0.f};
  const uint4* fw = sfrag + (((size_t)e*EV + wv*1024) << 1);
  const int a64 = q32*2 + hi;              // all 64 lanes load: point q32, k-half hi
  const int hbase = q32*65;

  // ---- pass 1: FULL histogram (32 tiles/wave; 4 waves cover all 4096 pts) ----
  {
    uint4 f0 = fw[a64];
    uint4 f1 = fw[64  + a64];
    uint4 f2 = fw[128 + a64];
    uint4 f3 = fw[192 + a64];
    for (int tl=0; tl<32; tl+=4){
      P1BODY(f0, tl+0)
      P1BODY(f1, tl+1)
      P1BODY(f2, tl+2)
      P1BODY(f3, tl+3)
    }
  }
  __syncthreads();

  // ---- prefix: tau per query (8 threads/query, 8 packed words = 16 bins each) ----
  {
    int q = t >> 3, i = t & 7;
    int base = q*65 + i*8;
    unsigned cnt[16];
    #pragma unroll
    for (int w2=0; w2<8; ++w2){
      unsigned w = hist[base + w2];
      cnt[w2*2]   = w & 0xFFFFu;
      cnt[w2*2+1] = w >> 16;
    }
    unsigned cs = 0;
    #pragma unroll
    for (int k2=0;k2<16;++k2) cs += cnt[k2];
    unsigned ps = cs;
    #pragma unroll
    for (int d=1; d<8; d<<=1){
      unsigned o = __shfl_up(ps, d, 8);
      if ((t&7) >= d) ps += o;
    }
    if (ps >= 16u && (ps - cs) < 16u){
      unsigned run = ps - cs;
      unsigned B = 127;
      #pragma unroll
      for (int k2=0;k2<16;++k2){
        unsigned c2 = cnt[k2];
        bool hit = (run < 16u) && (run + c2 >= 16u);
        if (hit) B = (unsigned)(i*16 + k2);
        run += c2;
      }
      // bin 127 is open-ended (clamped): cannot bound its members -> force fallback
      tauL[q] = (B >= 127u) ? 0x7F800001u : ((BIN_LO + B + 1u) << 21);
    }
  }
  __syncthreads();
  const int tauS = (int)tauL[q32];         // signed compare: negatives (rounded self-d2) survive

  // ---- pass 2: full quarter scan (32 tiles), push survivor indices ----
  {
    uint4 f0 = fw[a64];
    uint4 f1 = fw[64  + a64];
    uint4 f2 = fw[128 + a64];
    uint4 f3 = fw[192 + a64];
    const int jb = wv*1024 + 4*hi;
    for (int tl=0; tl<32; tl+=4){
      P2BODY(f0, tl+0)
      P2BODY(f1, tl+1)
      P2BODY(f2, tl+2)
      P2BODY(f3, tl+3)
    }
  }
  __syncthreads();

  // ---- final: exact fp32 d^2 -> top-16; 8 helper lanes/query across wave pairs ----
  // wave w: queries (w&1)*16..+15 ; helper stride h8 = (w>>1)*4 + g  (g = l>>4)
  const int q16 = l & 15, g = l >> 4;
  const int qq = (wv & 1)*16 + q16;
  const int h8 = (wv >> 1)*4 + g;
  const int qlocf = qblk + qq;
  const float4 sqf = sg[(size_t)e*EV + qlocf];
  unsigned scn_raw = scnt[qq];
  unsigned int bp[16];
  #pragma unroll
  for (int k=0;k<16;++k) bp[k]=0xFFFFFFFFu;
  if (scn_raw > (unsigned)SCAP){
    // overflow fallback: exact scan of all EV points (correctness guarantee, cold)
    for (int jj=h8; jj<EV; jj+=8){
      float4 s4 = sg[(size_t)e*EV + jj];
      float dx = sqf.x-s4.x, dy = sqf.y-s4.y, dz = sqf.z-s4.z, dw = sqf.w-s4.w;
      float d2 = dx*dx + dy*dy + dz*dz + dw*dw;
      unsigned key = (__float_as_uint(d2) & 0xFFFFF000u) | (unsigned)jj;
      if (key < bp[15]) { BUBBLE16(key) }
    }
  } else {
    for (unsigned i=h8; i<scn_raw; i+=8){
      int jj = (int)slist[qq*SCAP + i];
      float4 s4 = sg[(size_t)e*EV + jj];
      float dx = sqf.x-s4.x, dy = sqf.y-s4.y, dz = sqf.z-s4.z, dw = sqf.w-s4.w;
      float d2 = dx*dx + dy*dy + dz*dz + dw*dw;
      unsigned key = (__float_as_uint(d2) & 0xFFFFF000u) | (unsigned)jj;
      BUBBLE16(key)
    }
  }

  // in-wave merge across the 4 helper lanes of each query (xor 16, then xor 32)
  #pragma unroll
  for (int st=0; st<2; ++st){
    const int msk = (st==0) ? 16 : 32;
    unsigned int ot[16];
    #pragma unroll
    for (int k=0;k<16;++k) ot[k] = (unsigned int)__shfl_xor((int)bp[k], msk, 64);
    MERGE16(ot)
  }

  // cross-wave-pair merge: waves 2/3 publish, waves 0/1 merge + aggregate
  if (wv >= 2 && l < 16){
    #pragma unroll
    for (int k=0;k<16;++k) mrg[(wv&1)*16 + l][k] = bp[k];
  }
  __syncthreads();
  if (wv >= 2) return;
  {
    unsigned int ot[16];
    #pragma unroll
    for (int k=0;k<16;++k) ot[k] = mrg[qq][k];
    MERGE16(ot)
  }

  // aggregation: lane (q16, g) owns features g*8..g*8+7 for all 16 neighbors
  float am[8], ax[8];
  #pragma unroll
  for (int p=0;p<8;++p){ am[p]=0.f; ax[p]=-3.4e38f; }
  const uint4* hb = (const uint4*)(hIn + (size_t)e*EV*32);
  #pragma unroll
  for (int i=0;i<16;++i){
    unsigned int key = bp[i];
    int j = (int)(key & 0xFFFu);
    float d2 = __uint_as_float(key & 0xFFFFF000u);
    float w = __expf(-10.f * d2);
    uint4 hv = hb[(size_t)j*4 + g];
    unsigned int uu[4] = {hv.x, hv.y, hv.z, hv.w};
    #pragma unroll
    for (int c2=0;c2<4;++c2){
      float flo = __uint_as_float(uu[c2] << 16);
      float fhi = __uint_as_float(uu[c2] & 0xFFFF0000u);
      float m0 = w*flo, m1 = w*fhi;
      am[c2*2]   += m0;                 am[c2*2+1] += m1;
      ax[c2*2]    = fmaxf(ax[c2*2],m0); ax[c2*2+1]  = fmaxf(ax[c2*2+1],m1);
    }
  }
  {
    unsigned short* Ur = Umini + ((size_t)e*EV + qlocf)*64;
    uint4 pm, px;
    pm.x = (unsigned)f2bf(am[0]*(1.f/16.f)) | ((unsigned)f2bf(am[1]*(1.f/16.f))<<16);
    pm.y = (unsigned)f2bf(am[2]*(1.f/16.f)) | ((unsigned)f2bf(am[3]*(1.f/16.f))<<16);
    pm.z = (unsigned)f2bf(am[4]*(1.f/16.f)) | ((unsigned)f2bf(am[5]*(1.f/16.f))<<16);
    pm.w = (unsigned)f2bf(am[6]*(1.f/16.f)) | ((unsigned)f2bf(am[7]*(1.f/16.f))<<16);
    px.x = (unsigned)f2bf(ax[0]) | ((unsigned)f2bf(ax[1])<<16);
    px.y = (unsigned)f2bf(ax[2]) | ((unsigned)f2bf(ax[3])<<16);
    px.z = (unsigned)f2bf(ax[4]) | ((unsigned)f2bf(ax[5])<<16);
    px.w = (unsigned)f2bf(ax[6]) | ((unsigned)f2bf(ax[7])<<16);
    *(uint4*)(Ur +  0 + g*8) = pm;
    *(uint4*)(Ur + 32 + g*8) = px;
  }
}

// ---------------- Kernel C: x_new = [bf16(x)|Umini] @ Wo + bo ; residual ; LayerNorm ----
__global__ __launch_bounds__(256, 4) void kC(
    const unsigned short* __restrict__ Umini, const unsigned short* __restrict__ WoT,
    const float* __restrict__ bo, const float* __restrict__ x,
    const float* __restrict__ gamma, const float* __restrict__ beta,
    float* __restrict__ out)
{
  __shared__ unsigned short At[64*40];    // [64 rows][32k padded to 40]
  __shared__ unsigned short Bt[256*40];   // [256 cols][32k padded to 40]
  __shared__ float ps[64*4], pq[64*4];
  const int t = threadIdx.x;
  const int r0 = blockIdx.x * 64;
  const int l = t & 63, wv = t >> 6;
  const int lq = l & 15, g = l >> 4;
  f32x4 acc[4][4];
  const f32x4 zero = {0.f,0.f,0.f,0.f};
  #pragma unroll
  for (int m=0;m<4;++m)
    #pragma unroll
    for (int n=0;n<4;++n) acc[m][n] = zero;

  for (int kk=0; kk<10; ++kk){
    const int k0 = kk*32;
    __syncthreads();
    { // stage A: k<256 from x (fp32 -> bf16 via v_cvt_pk), else from Umini
      int row = t >> 2, ko = (t & 3)*8;
      uint4 av;
      if (k0 < 256){
        const float4* xr = (const float4*)(x + (size_t)(r0+row)*256 + k0 + ko);
        float4 u0 = xr[0], u1 = xr[1];
        unsigned p0,p1,p2,p3;
        asm("v_cvt_pk_bf16_f32 %0, %1, %2" : "=v"(p0) : "v"(u0.x), "v"(u0.y));
        asm("v_cvt_pk_bf16_f32 %0, %1, %2" : "=v"(p1) : "v"(u0.z), "v"(u0.w));
        asm("v_cvt_pk_bf16_f32 %0, %1, %2" : "=v"(p2) : "v"(u1.x), "v"(u1.y));
        asm("v_cvt_pk_bf16_f32 %0, %1, %2" : "=v"(p3) : "v"(u1.z), "v"(u1.w));
        av.x = p0; av.y = p1; av.z = p2; av.w = p3;
      } else {
        av = *(const uint4*)(Umini + (size_t)(r0+row)*64 + (k0-256) + ko);
      }
      *(uint4*)(At + row*40 + ko) = av;
    }
    { // stage B^T from pre-transposed WoT [256 cols][320 k] bf16
      int col = t;
      const uint4* src = (const uint4*)(WoT + (size_t)col*320 + k0);
      #pragma unroll
      for (int j=0;j<4;++j) *(uint4*)(Bt + col*40 + j*8) = src[j];
    }
    __syncthreads();
    short8 a[4], b[4];
    #pragma unroll
    for (int m=0;m<4;++m) a[m] = *(const short8*)(At + (16*m+lq)*40 + g*8);
    #pragma unroll
    for (int n=0;n<4;++n) b[n] = *(const short8*)(Bt + (wv*64 + 16*n + lq)*40 + g*8);
    #pragma unroll
    for (int m=0;m<4;++m)
      #pragma unroll
      for (int n=0;n<4;++n)
        acc[m][n] = __builtin_amdgcn_mfma_f32_16x16x32_bf16(a[m], b[n], acc[m][n], 0, 0, 0);
  }

  // epilogue: + bo + x(residual), LayerNorm over 256 cols
  float bo_n[4], ga_n[4], be_n[4];
  #pragma unroll
  for (int n=0;n<4;++n){
    int colg = wv*64 + 16*n + lq;
    bo_n[n] = bo[colg]; ga_n[n] = gamma[colg]; be_n[n] = beta[colg];
  }
  float pr[4][4], pr2[4][4];
  #pragma unroll
  for (int m=0;m<4;++m){
    #pragma unroll
    for (int rg=0;rg<4;++rg){
      int rowg = r0 + 16*m + g*4 + rg;
      float sum=0.f, sq=0.f;
      #pragma unroll
      for (int n=0;n<4;++n){
        int colg = wv*64 + 16*n + lq;
        float y = acc[m][n][rg] + bo_n[n] + x[(size_t)rowg*256 + colg];
        acc[m][n][rg] = y;
        sum += y; sq += y*y;
      }
      sum += __shfl_xor(sum,1); sq += __shfl_xor(sq,1);
      sum += __shfl_xor(sum,2); sq += __shfl_xor(sq,2);
      sum += __shfl_xor(sum,4); sq += __shfl_xor(sq,4);
      sum += __shfl_xor(sum,8); sq += __shfl_xor(sq,8);
      pr[m][rg]=sum; pr2[m][rg]=sq;
    }
  }
  if (lq == 0){
    #pragma unroll
    for (int m=0;m<4;++m)
      #pragma unroll
      for (int rg=0;rg<4;++rg){
        int rowl = 16*m + g*4 + rg;
        ps[rowl*4 + wv] = pr[m][rg];
        pq[rowl*4 + wv] = pr2[m][rg];
      }
  }
  __syncthreads();
  #pragma unroll
  for (int m=0;m<4;++m){
    #pragma unroll
    for (int rg=0;rg<4;++rg){
      int rowl = 16*m + g*4 + rg;
      float sum = ps[rowl*4+0]+ps[rowl*4+1]+ps[rowl*4+2]+ps[rowl*4+3];
      float sq  = pq[rowl*4+0]+pq[rowl*4+1]+pq[rowl*4+2]+pq[rowl*4+3];
      float mu  = sum * (1.f/256.f);
      float var = sq * (1.f/256.f) - mu*mu;
      float inv = rsqrtf(var + 1e-5f);
      int rowg = r0 + rowl;
      #pragma unroll
      for (int n=0;n<4;++n){
        int colg = wv*64 + 16*n + lq;
        out[(size_t)rowg*256 + colg] = ga_n[n]*(acc[m][n][rg] - mu)*inv + be_n[n];
      }
    }
  }
}

extern "C" void kernel_launch(void* const* d_in, const int* in_sizes, int n_in,
                              void* d_out, int out_size, void* d_ws, size_t ws_size,
                              hipStream_t stream)
{
  const float* x     = (const float*)d_in[0];
  // d_in[1] = batch_index (block-sorted equal events; unused)
  const float* Ws    = (const float*)d_in[2];
  const float* bs    = (const float*)d_in[3];
  const float* Wh    = (const float*)d_in[4];
  const float* bh    = (const float*)d_in[5];
  const float* Wo    = (const float*)d_in[6];
  const float* bo    = (const float*)d_in[7];
  const float* gamma = (const float*)d_in[8];
  const float* beta  = (const float*)d_in[9];
  float* out = (float*)d_out;

  char* ws = (char*)d_ws;
  float*          sBuf  = (float*)ws;                        // N*4 f32    = 0.5 MB
  uint4*          sfrag = (uint4*)(ws + 524288);             // N*32 B     = 1 MB
  unsigned short* hBuf  = (unsigned short*)(ws + 1572864);   // N*32 bf16  = 2 MB
  unsigned short* Umini = (unsigned short*)(ws + 3670016);   // N*64 bf16  = 4 MB
  unsigned short* WoT   = (unsigned short*)(ws + 7864320);   // 256*320 bf16 = 160 KB

  kA<<<dim3(N_TOT/64 + 10), dim3(256), 0, stream>>>(x, Ws, bs, Wh, bh, Wo,
                                                    sBuf, sfrag, hBuf, (unsigned int*)WoT);
  kB<<<dim3(N_TOT/32), dim3(256), 0, stream>>>(sBuf, sfrag, hBuf, Umini);
  kC<<<dim3(N_TOT/64), dim3(256), 0, stream>>>(Umini, WoT, bo, x, gamma, beta, out);
}

// Round 16
// 125.246 us; speedup vs baseline: 1.1781x; 1.1781x over previous
//
#include <hip/hip_runtime.h>
#include <stdint.h>

typedef short short8 __attribute__((ext_vector_type(8)));
typedef float f32x4 __attribute__((ext_vector_type(4)));
typedef float f32x16 __attribute__((ext_vector_type(16)));
typedef unsigned short u16;

#define N_TOT 32768
#define EV 4096

__device__ __forceinline__ u16 f2bf(float f){
  unsigned int x = __float_as_uint(f);
  x += 0x7FFFu + ((x >> 16) & 1u);
  return (u16)(x >> 16);
}
__device__ __forceinline__ unsigned umin_(unsigned a, unsigned b){ return a<b?a:b; }

// ---------------- Kernel A: fused stage+s (single x pass), h (bf16 MFMA); +kW fold ---
__global__ __launch_bounds__(256, 3) void kA(
    const float* __restrict__ x, const float* __restrict__ Ws,
    const float* __restrict__ bs, const float* __restrict__ Wh,
    const float* __restrict__ bh, const float* __restrict__ Wo,
    float* __restrict__ sOut, uint4* __restrict__ sfrag,
    unsigned short* __restrict__ hOut, unsigned int* __restrict__ WoT2)
{
  if (blockIdx.x >= N_TOT/64){                 // folded kW: Wo [320][256] f32 -> WoT [256][320] bf16
    const int kb = (blockIdx.x - N_TOT/64) * 32;
    const int c = threadIdx.x;
    unsigned int prev = 0;
    for (int k=0;k<32;++k){
      float v = Wo[(size_t)(kb+k)*256 + c];
      u16 h = f2bf(v);
      if (k & 1) WoT2[(size_t)c*160 + ((kb+k)>>1)] = prev | ((unsigned)h<<16);
      else       prev = (unsigned)h;
    }
    return;
  }
  __shared__ u16 xh[64*264];     // bf16 x tile [row][k], stride 264 u16 (33.8KB)
  __shared__ u16 whT[32*264];    // bf16 Wh^T [col][k], stride 264 (16.9KB)
  const int t = threadIdx.x;
  const int wv = t >> 6, l = t & 63;
  const int r0 = blockIdx.x * 64;

  // stage whT: Wh [256][32] f32 -> whT[col][k] bf16
  #pragma unroll
  for (int i=0;i<32;++i){
    int k = i*8 + (t>>5);
    int col = t & 31;
    whT[col*264 + k] = f2bf(Wh[(size_t)k*32 + col]);
  }

  // fused: stage xh (bf16) + s fp32 partials, ONE pass over x.
  {
    const int row = t >> 2, c40 = t & 3;
    const float4* xr = (const float4*)(x + (size_t)(r0+row)*256);
    const float4* wsr = (const float4*)Ws;   // Ws[k][0..3]
    float a0=0.f,a1=0.f,a2=0.f,a3=0.f;
    #pragma unroll
    for (int i=0;i<16;++i){
      int c4 = c40 + i*4;
      float4 xv = xr[c4];
      unsigned p0,p1;
      asm("v_cvt_pk_bf16_f32 %0, %1, %2" : "=v"(p0) : "v"(xv.x), "v"(xv.y));
      asm("v_cvt_pk_bf16_f32 %0, %1, %2" : "=v"(p1) : "v"(xv.z), "v"(xv.w));
      uint2 pk = {p0, p1};
      *(uint2*)&xh[row*264 + c4*4] = pk;
      float4 w0 = wsr[c4*4+0], w1 = wsr[c4*4+1], w2 = wsr[c4*4+2], w3 = wsr[c4*4+3];
      a0 += xv.x*w0.x + xv.y*w1.x + xv.z*w2.x + xv.w*w3.x;
      a1 += xv.x*w0.y + xv.y*w1.y + xv.z*w2.y + xv.w*w3.y;
      a2 += xv.x*w0.z + xv.y*w1.z + xv.z*w2.z + xv.w*w3.z;
      a3 += xv.x*w0.w + xv.y*w1.w + xv.z*w2.w + xv.w*w3.w;
    }
    a0 += __shfl_xor(a0,1); a0 += __shfl_xor(a0,2);
    a1 += __shfl_xor(a1,1); a1 += __shfl_xor(a1,2);
    a2 += __shfl_xor(a2,1); a2 += __shfl_xor(a2,2);
    a3 += __shfl_xor(a3,1); a3 += __shfl_xor(a3,2);
    if (c40 == 0){
      float4 sv = { a0+bs[0], a1+bs[1], a2+bs[2], a3+bs[3] };
      ((float4*)sOut)[r0 + row] = sv;
      // A-side (point) fragment: k0-7 = [hi4,hi4]; k8-15 = [lo4, nh, nl, 1, 1]
      u16 h0=f2bf(sv.x), h1=f2bf(sv.y), h2=f2bf(sv.z), h3=f2bf(sv.w);
      float e0 = sv.x - __uint_as_float((unsigned)h0<<16);
      float e1 = sv.y - __uint_as_float((unsigned)h1<<16);
      float e2 = sv.z - __uint_as_float((unsigned)h2<<16);
      float e3 = sv.w - __uint_as_float((unsigned)h3<<16);
      u16 l0=f2bf(e0), l1=f2bf(e1), l2=f2bf(e2), l3=f2bf(e3);
      float n = sv.x*sv.x + sv.y*sv.y + sv.z*sv.z + sv.w*sv.w;
      u16 nh = f2bf(n);
      u16 nl = f2bf(n - __uint_as_float((unsigned)nh<<16));
      uint4 w0, w1;
      w0.x = (unsigned)h0 | ((unsigned)h1<<16);
      w0.y = (unsigned)h2 | ((unsigned)h3<<16);
      w0.z = w0.x; w0.w = w0.y;
      w1.x = (unsigned)l0 | ((unsigned)l1<<16);
      w1.y = (unsigned)l2 | ((unsigned)l3<<16);
      w1.z = (unsigned)nh | ((unsigned)nl<<16);
      w1.w = 0x3F803F80u;                       // 1.0, 1.0 (pairs with B's si2 hi/lo)
      sfrag[(size_t)(r0+row)*2 + 0] = w0;
      sfrag[(size_t)(r0+row)*2 + 1] = w1;
    }
  }
  __syncthreads();

  // h = x @ Wh via MFMA: wave wv -> rows 16wv..16wv+15; 2 col-tiles of 16.
  {
    const int lq = l & 15, g = l >> 4;
    const f32x4 zero = {0.f,0.f,0.f,0.f};
    f32x4 h0 = zero, h1 = zero;
    #pragma unroll
    for (int ks=0; ks<8; ++ks){
      short8 a  = *(const short8*)&xh[(wv*16+lq)*264 + ks*32 + g*8];
      short8 b0 = *(const short8*)&whT[lq*264       + ks*32 + g*8];
      short8 b1 = *(const short8*)&whT[(16+lq)*264  + ks*32 + g*8];
      h0 = __builtin_amdgcn_mfma_f32_16x16x32_bf16(a, b0, h0, 0,0,0);
      h1 = __builtin_amdgcn_mfma_f32_16x16x32_bf16(a, b1, h1, 0,0,0);
    }
    float bv0 = bh[lq], bv1 = bh[16+lq];
    #pragma unroll
    for (int rg=0; rg<4; ++rg){
      int rowg = r0 + wv*16 + g*4 + rg;
      hOut[(size_t)rowg*32 + lq]      = f2bf(h0[rg] + bv0);
      hOut[(size_t)rowg*32 + 16 + lq] = f2bf(h1[rg] + bv1);
    }
  }
}

// ---------------- Kernel B: 32x32x16-MFMA radix-select kNN ---------------------------
// 1024 blocks (= 4/CU); block: 32 queries, 4 waves each scanning a 1024-pt quarter
// in 32-pt tiles (mfma_f32_32x32x16_bf16, K=16).
// Pass 1 (8 tiles/wave = quarter sample): packed 128-bin quarter-octave hist -> tau
//   (subset tau is a valid upper bound; survivors ~130/query).
// Pass 2 (32 tiles): signed-compare survivor push to slist; scnt counts ALL.
// Final (ALL 4 waves): 8 helper lanes/query (wave w: queries (w&1)*16.., strides
//   (w>>1)*4+g); exact fp32 d^2 (overflow -> full scan), bubble, xor16/32 in-wave
//   merge + cross-wave-pair MERGE16 via mrg; waves 0/1 aggregate.
#define BUBBLE16(v)                                              \
  { _Pragma("unroll")                                            \
    for (int k=0;k<16;++k){                                      \
      unsigned int mn = (v) < bp[k] ? (v) : bp[k];               \
      unsigned int mx = (v) < bp[k] ? bp[k] : (v);               \
      bp[k] = mn; (v) = mx;                                      \
    } }

#define MERGE16(OT)                                              \
  { unsigned int c[16];                                          \
    _Pragma("unroll")                                            \
    for (int k=0;k<16;++k){ unsigned int b2 = (OT)[15-k];        \
      c[k] = bp[k] < b2 ? bp[k] : b2; }                          \
    _Pragma("unroll")                                            \
    for (int d=8; d>=1; d>>=1){                                  \
      _Pragma("unroll")                                          \
      for (int i=0;i<16;++i){                                    \
        if ((i & d) == 0){                                       \
          unsigned int lo = c[i] < c[i+d] ? c[i] : c[i+d];       \
          unsigned int hi = c[i] < c[i+d] ? c[i+d] : c[i];       \
          c[i] = lo; c[i+d] = hi;                                \
        }                                                        \
      }                                                          \
    }                                                            \
    _Pragma("unroll")                                            \
    for (int k=0;k<16;++k) bp[k] = c[k]; }

#define SCAP 448
#define BIN_LO 440u   // 110*4: window start (exp 110 -> d2 ~ 4e-6)

#define P1BODY(F, TL)                                            \
  { union { uint4 q; short8 v; } au; au.q = (F);                 \
    (F) = fw[(size_t)((TL)+4)*64 + a64];                         \
    f32x16 acc = __builtin_amdgcn_mfma_f32_32x32x16_bf16(au.v, bq, zacc, 0,0,0); \
    _Pragma("unroll")                                            \
    for (int rg=0; rg<16; ++rg){                                 \
      unsigned u = __float_as_uint(fmaxf(acc[rg],0.f));          \
      unsigned q21 = u >> 21;                                    \
      unsigned b = (q21 < BIN_LO) ? 0u : umin_(q21 - BIN_LO, 127u); \
      atomicAdd(&hist[hbase + (b>>1)], (b&1u) ? 0x10000u : 1u);  \
    } }

#define P2BODY(F, TL)                                            \
  { union { uint4 q; short8 v; } au; au.q = (F);                 \
    (F) = fw[(size_t)((TL)+4)*64 + a64];                         \
    f32x16 acc = __builtin_amdgcn_mfma_f32_32x32x16_bf16(au.v, bq, zacc, 0,0,0); \
    const int jb2 = jb + (TL)*32;                                \
    _Pragma("unroll")                                            \
    for (int rg=0; rg<16; ++rg){                                 \
      int u = (int)__float_as_uint(acc[rg]);                     \
      if (u < tauS){                                             \
        int j = jb2 + (rg&3) + 8*(rg>>2);                        \
        unsigned idx = atomicAdd(&scnt[q32], 1u);                \
        if (idx < (unsigned)SCAP) slist[q32*SCAP + idx] = (u16)j; \
      }                                                          \
    } }

__global__ __launch_bounds__(256, 4) void kB(
    const float* __restrict__ sIn, const uint4* __restrict__ sfrag,
    const unsigned short* __restrict__ hIn, unsigned short* __restrict__ Umini)
{
  __shared__ unsigned int hist[32*65];     // 128 bins packed 2-per-word, stride 65 (8.3KB)
  __shared__ u16 slist[32*SCAP];           // per-query survivor indices (28KB)
  __shared__ unsigned int scnt[32];
  __shared__ unsigned int tauL[32];
  __shared__ unsigned int mrg[32][17];     // cross-wave-pair merge lists (2.2KB)
  const int t = threadIdx.x;
  const int wv = t >> 6, l = t & 63;
  const int e = blockIdx.x >> 7;           // 128 blocks/event
  const int qblk = (blockIdx.x & 127) * 32;
  const int q32 = l & 31, hi = l >> 5;
  const int qloc = qblk + q32;

  const float4* sg = (const float4*)sIn;
  const float4 sq = sg[(size_t)e*EV + qloc];
  const float si2 = sq.x*sq.x + sq.y*sq.y + sq.z*sq.z + sq.w*sq.w;

  // B (query col q32) fragment: hi=0 -> k0-7 [-2s_hi4 | -2s_lo4]; hi=1 -> k8-15 [-2s_hi4 | 1,1,sh,sl]
  union BU { u16 u[8]; short8 v; } bu;
  {
    float tx=-2.f*sq.x, ty=-2.f*sq.y, tz=-2.f*sq.z, tw=-2.f*sq.w;
    u16 h0=f2bf(tx), h1=f2bf(ty), h2=f2bf(tz), h3=f2bf(tw);
    bu.u[0]=h0; bu.u[1]=h1; bu.u[2]=h2; bu.u[3]=h3;
    if (hi==0){
      float e0 = tx - __uint_as_float((unsigned)h0<<16);
      float e1 = ty - __uint_as_float((unsigned)h1<<16);
      float e2 = tz - __uint_as_float((unsigned)h2<<16);
      float e3 = tw - __uint_as_float((unsigned)h3<<16);
      bu.u[4]=f2bf(e0); bu.u[5]=f2bf(e1); bu.u[6]=f2bf(e2); bu.u[7]=f2bf(e3);
    } else {
      u16 sh = f2bf(si2);
      u16 sl = f2bf(si2 - __uint_as_float((unsigned)sh<<16));
      bu.u[4]=0x3F80; bu.u[5]=0x3F80; bu.u[6]=sh; bu.u[7]=sl;
    }
  }
  const short8 bq = bu.v;

  // zero histogram + counters
  for (int i=t; i<32*65; i+=256) hist[i]=0;
  if (t < 32) scnt[t] = 0;
  __syncthreads();

  const f32x16 zacc = {0.f,0.f,0.f,0.f,0.f,0.f,0.f,0.f,0.f,0.f,0.f,0.f,0.f,0.f,0.f,0.f};
  const uint4* fw = sfrag + (((size_t)e*EV + wv*1024) << 1);
  const int a64 = q32*2 + hi;              // all 64 lanes load: point q32, k-half hi
  const int hbase = q32*65;

  // ---- pass 1: packed histogram over first 256 pts of the quarter (8 tiles) ----
  {
    uint4 f0 = fw[a64];
    uint4 f1 = fw[64  + a64];
    uint4 f2 = fw[128 + a64];
    uint4 f3 = fw[192 + a64];
    for (int tl=0; tl<8; tl+=4){
      P1BODY(f0, tl+0)
      P1BODY(f1, tl+1)
      P1BODY(f2, tl+2)
      P1BODY(f3, tl+3)
    }
  }
  __syncthreads();

  // ---- prefix: tau per query (8 threads/query, 8 packed words = 16 bins each) ----
  {
    int q = t >> 3, i = t & 7;
    int base = q*65 + i*8;
    unsigned cnt[16];
    #pragma unroll
    for (int w2=0; w2<8; ++w2){
      unsigned w = hist[base + w2];
      cnt[w2*2]   = w & 0xFFFFu;
      cnt[w2*2+1] = w >> 16;
    }
    unsigned cs = 0;
    #pragma unroll
    for (int k2=0;k2<16;++k2) cs += cnt[k2];
    unsigned ps = cs;
    #pragma unroll
    for (int d=1; d<8; d<<=1){
      unsigned o = __shfl_up(ps, d, 8);
      if ((t&7) >= d) ps += o;
    }
    if (ps >= 16u && (ps - cs) < 16u){
      unsigned run = ps - cs;
      unsigned B = 127;
      #pragma unroll
      for (int k2=0;k2<16;++k2){
        unsigned c2 = cnt[k2];
        bool hit = (run < 16u) && (run + c2 >= 16u);
        if (hit) B = (unsigned)(i*16 + k2);
        run += c2;
      }
      // bin 127 is open-ended (clamped): cannot bound its members -> force fallback
      tauL[q] = (B >= 127u) ? 0x7F800001u : ((BIN_LO + B + 1u) << 21);
    }
  }
  __syncthreads();
  const int tauS = (int)tauL[q32];         // signed compare: negatives (rounded self-d2) survive

  // ---- pass 2: full quarter scan (32 tiles), push survivor indices ----
  {
    uint4 f0 = fw[a64];
    uint4 f1 = fw[64  + a64];
    uint4 f2 = fw[128 + a64];
    uint4 f3 = fw[192 + a64];
    const int jb = wv*1024 + 4*hi;
    for (int tl=0; tl<32; tl+=4){
      P2BODY(f0, tl+0)
      P2BODY(f1, tl+1)
      P2BODY(f2, tl+2)
      P2BODY(f3, tl+3)
    }
  }
  __syncthreads();

  // ---- final: exact fp32 d^2 -> top-16; 8 helper lanes/query across wave pairs ----
  // wave w: queries (w&1)*16..+15 ; helper stride h8 = (w>>1)*4 + g  (g = l>>4)
  const int q16 = l & 15, g = l >> 4;
  const int qq = (wv & 1)*16 + q16;
  const int h8 = (wv >> 1)*4 + g;
  const int qlocf = qblk + qq;
  const float4 sqf = sg[(size_t)e*EV + qlocf];
  unsigned scn_raw = scnt[qq];
  unsigned int bp[16];
  #pragma unroll
  for (int k=0;k<16;++k) bp[k]=0xFFFFFFFFu;
  if (scn_raw > (unsigned)SCAP){
    // overflow fallback: exact scan of all EV points (correctness guarantee, cold)
    for (int jj=h8; jj<EV; jj+=8){
      float4 s4 = sg[(size_t)e*EV + jj];
      float dx = sqf.x-s4.x, dy = sqf.y-s4.y, dz = sqf.z-s4.z, dw = sqf.w-s4.w;
      float d2 = dx*dx + dy*dy + dz*dz + dw*dw;
      unsigned key = (__float_as_uint(d2) & 0xFFFFF000u) | (unsigned)jj;
      if (key < bp[15]) { BUBBLE16(key) }
    }
  } else {
    for (unsigned i=h8; i<scn_raw; i+=8){
      int jj = (int)slist[qq*SCAP + i];
      float4 s4 = sg[(size_t)e*EV + jj];
      float dx = sqf.x-s4.x, dy = sqf.y-s4.y, dz = sqf.z-s4.z, dw = sqf.w-s4.w;
      float d2 = dx*dx + dy*dy + dz*dz + dw*dw;
      unsigned key = (__float_as_uint(d2) & 0xFFFFF000u) | (unsigned)jj;
      BUBBLE16(key)
    }
  }

  // in-wave merge across the 4 helper lanes of each query (xor 16, then xor 32)
  #pragma unroll
  for (int st=0; st<2; ++st){
    const int msk = (st==0) ? 16 : 32;
    unsigned int ot[16];
    #pragma unroll
    for (int k=0;k<16;++k) ot[k] = (unsigned int)__shfl_xor((int)bp[k], msk, 64);
    MERGE16(ot)
  }

  // cross-wave-pair merge: waves 2/3 publish, waves 0/1 merge + aggregate
  if (wv >= 2 && l < 16){
    #pragma unroll
    for (int k=0;k<16;++k) mrg[(wv&1)*16 + l][k] = bp[k];
  }
  __syncthreads();
  if (wv >= 2) return;
  {
    unsigned int ot[16];
    #pragma unroll
    for (int k=0;k<16;++k) ot[k] = mrg[qq][k];
    MERGE16(ot)
  }

  // aggregation: lane (q16, g) owns features g*8..g*8+7 for all 16 neighbors
  float am[8], ax[8];
  #pragma unroll
  for (int p=0;p<8;++p){ am[p]=0.f; ax[p]=-3.4e38f; }
  const uint4* hb = (const uint4*)(hIn + (size_t)e*EV*32);
  #pragma unroll
  for (int i=0;i<16;++i){
    unsigned int key = bp[i];
    int j = (int)(key & 0xFFFu);
    float d2 = __uint_as_float(key & 0xFFFFF000u);
    float w = __expf(-10.f * d2);
    uint4 hv = hb[(size_t)j*4 + g];
    unsigned int uu[4] = {hv.x, hv.y, hv.z, hv.w};
    #pragma unroll
    for (int c2=0;c2<4;++c2){
      float flo = __uint_as_float(uu[c2] << 16);
      float fhi = __uint_as_float(uu[c2] & 0xFFFF0000u);
      float m0 = w*flo, m1 = w*fhi;
      am[c2*2]   += m0;                 am[c2*2+1] += m1;
      ax[c2*2]    = fmaxf(ax[c2*2],m0); ax[c2*2+1]  = fmaxf(ax[c2*2+1],m1);
    }
  }
  {
    unsigned short* Ur = Umini + ((size_t)e*EV + qlocf)*64;
    uint4 pm, px;
    pm.x = (unsigned)f2bf(am[0]*(1.f/16.f)) | ((unsigned)f2bf(am[1]*(1.f/16.f))<<16);
    pm.y = (unsigned)f2bf(am[2]*(1.f/16.f)) | ((unsigned)f2bf(am[3]*(1.f/16.f))<<16);
    pm.z = (unsigned)f2bf(am[4]*(1.f/16.f)) | ((unsigned)f2bf(am[5]*(1.f/16.f))<<16);
    pm.w = (unsigned)f2bf(am[6]*(1.f/16.f)) | ((unsigned)f2bf(am[7]*(1.f/16.f))<<16);
    px.x = (unsigned)f2bf(ax[0]) | ((unsigned)f2bf(ax[1])<<16);
    px.y = (unsigned)f2bf(ax[2]) | ((unsigned)f2bf(ax[3])<<16);
    px.z = (unsigned)f2bf(ax[4]) | ((unsigned)f2bf(ax[5])<<16);
    px.w = (unsigned)f2bf(ax[6]) | ((unsigned)f2bf(ax[7])<<16);
    *(uint4*)(Ur +  0 + g*8) = pm;
    *(uint4*)(Ur + 32 + g*8) = px;
  }
}

// ---------------- Kernel C: x_new = [bf16(x)|Umini] @ Wo + bo ; residual ; LayerNorm ----
__global__ __launch_bounds__(256, 4) void kC(
    const unsigned short* __restrict__ Umini, const unsigned short* __restrict__ WoT,
    const float* __restrict__ bo, const float* __restrict__ x,
    const float* __restrict__ gamma, const float* __restrict__ beta,
    float* __restrict__ out)
{
  __shared__ unsigned short At[64*40];    // [64 rows][32k padded to 40]
  __shared__ unsigned short Bt[256*40];   // [256 cols][32k padded to 40]
  __shared__ float ps[64*4], pq[64*4];
  const int t = threadIdx.x;
  const int r0 = blockIdx.x * 64;
  const int l = t & 63, wv = t >> 6;
  const int lq = l & 15, g = l >> 4;
  f32x4 acc[4][4];
  const f32x4 zero = {0.f,0.f,0.f,0.f};
  #pragma unroll
  for (int m=0;m<4;++m)
    #pragma unroll
    for (int n=0;n<4;++n) acc[m][n] = zero;

  for (int kk=0; kk<10; ++kk){
    const int k0 = kk*32;
    __syncthreads();
    { // stage A: k<256 from x (fp32 -> bf16 via v_cvt_pk), else from Umini
      int row = t >> 2, ko = (t & 3)*8;
      uint4 av;
      if (k0 < 256){
        const float4* xr = (const float4*)(x + (size_t)(r0+row)*256 + k0 + ko);
        float4 u0 = xr[0], u1 = xr[1];
        unsigned p0,p1,p2,p3;
        asm("v_cvt_pk_bf16_f32 %0, %1, %2" : "=v"(p0) : "v"(u0.x), "v"(u0.y));
        asm("v_cvt_pk_bf16_f32 %0, %1, %2" : "=v"(p1) : "v"(u0.z), "v"(u0.w));
        asm("v_cvt_pk_bf16_f32 %0, %1, %2" : "=v"(p2) : "v"(u1.x), "v"(u1.y));
        asm("v_cvt_pk_bf16_f32 %0, %1, %2" : "=v"(p3) : "v"(u1.z), "v"(u1.w));
        av.x = p0; av.y = p1; av.z = p2; av.w = p3;
      } else {
        av = *(const uint4*)(Umini + (size_t)(r0+row)*64 + (k0-256) + ko);
      }
      *(uint4*)(At + row*40 + ko) = av;
    }
    { // stage B^T from pre-transposed WoT [256 cols][320 k] bf16
      int col = t;
      const uint4* src = (const uint4*)(WoT + (size_t)col*320 + k0);
      #pragma unroll
      for (int j=0;j<4;++j) *(uint4*)(Bt + col*40 + j*8) = src[j];
    }
    __syncthreads();
    short8 a[4], b[4];
    #pragma unroll
    for (int m=0;m<4;++m) a[m] = *(const short8*)(At + (16*m+lq)*40 + g*8);
    #pragma unroll
    for (int n=0;n<4;++n) b[n] = *(const short8*)(Bt + (wv*64 + 16*n + lq)*40 + g*8);
    #pragma unroll
    for (int m=0;m<4;++m)
      #pragma unroll
      for (int n=0;n<4;++n)
        acc[m][n] = __builtin_amdgcn_mfma_f32_16x16x32_bf16(a[m], b[n], acc[m][n], 0, 0, 0);
  }

  // epilogue: + bo + x(residual), LayerNorm over 256 cols
  float bo_n[4], ga_n[4], be_n[4];
  #pragma unroll
  for (int n=0;n<4;++n){
    int colg = wv*64 + 16*n + lq;
    bo_n[n] = bo[colg]; ga_n[n] = gamma[colg]; be_n[n] = beta[colg];
  }
  float pr[4][4], pr2[4][4];
  #pragma unroll
  for (int m=0;m<4;++m){
    #pragma unroll
    for (int rg=0;rg<4;++rg){
      int rowg = r0 + 16*m + g*4 + rg;
      float sum=0.f, sq=0.f;
      #pragma unroll
      for (int n=0;n<4;++n){
        int colg = wv*64 + 16*n + lq;
        float y = acc[m][n][rg] + bo_n[n] + x[(size_t)rowg*256 + colg];
        acc[m][n][rg] = y;
        sum += y; sq += y*y;
      }
      sum += __shfl_xor(sum,1); sq += __shfl_xor(sq,1);
      sum += __shfl_xor(sum,2); sq += __shfl_xor(sq,2);
      sum += __shfl_xor(sum,4); sq += __shfl_xor(sq,4);
      sum += __shfl_xor(sum,8); sq += __shfl_xor(sq,8);
      pr[m][rg]=sum; pr2[m][rg]=sq;
    }
  }
  if (lq == 0){
    #pragma unroll
    for (int m=0;m<4;++m)
      #pragma unroll
      for (int rg=0;rg<4;++rg){
        int rowl = 16*m + g*4 + rg;
        ps[rowl*4 + wv] = pr[m][rg];
        pq[rowl*4 + wv] = pr2[m][rg];
      }
  }
  __syncthreads();
  #pragma unroll
  for (int m=0;m<4;++m){
    #pragma unroll
    for (int rg=0;rg<4;++rg){
      int rowl = 16*m + g*4 + rg;
      float sum = ps[rowl*4+0]+ps[rowl*4+1]+ps[rowl*4+2]+ps[rowl*4+3];
      float sq  = pq[rowl*4+0]+pq[rowl*4+1]+pq[rowl*4+2]+pq[rowl*4+3];
      float mu  = sum * (1.f/256.f);
      float var = sq * (1.f/256.f) - mu*mu;
      float inv = rsqrtf(var + 1e-5f);
      int rowg = r0 + rowl;
      #pragma unroll
      for (int n=0;n<4;++n){
        int colg = wv*64 + 16*n + lq;
        out[(size_t)rowg*256 + colg] = ga_n[n]*(acc[m][n][rg] - mu)*inv + be_n[n];
      }
    }
  }
}

extern "C" void kernel_launch(void* const* d_in, const int* in_sizes, int n_in,
                              void* d_out, int out_size, void* d_ws, size_t ws_size,
                              hipStream_t stream)
{
  const float* x     = (const float*)d_in[0];
  // d_in[1] = batch_index (block-sorted equal events; unused)
  const float* Ws    = (const float*)d_in[2];
  const float* bs    = (const float*)d_in[3];
  const float* Wh    = (const float*)d_in[4];
  const float* bh    = (const float*)d_in[5];
  const float* Wo    = (const float*)d_in[6];
  const float* bo    = (const float*)d_in[7];
  const float* gamma = (const float*)d_in[8];
  const float* beta  = (const float*)d_in[9];
  float* out = (float*)d_out;

  char* ws = (char*)d_ws;
  float*          sBuf  = (float*)ws;                        // N*4 f32    = 0.5 MB
  uint4*          sfrag = (uint4*)(ws + 524288);             // N*32 B     = 1 MB
  unsigned short* hBuf  = (unsigned short*)(ws + 1572864);   // N*32 bf16  = 2 MB
  unsigned short* Umini = (unsigned short*)(ws + 3670016);   // N*64 bf16  = 4 MB
  unsigned short* WoT   = (unsigned short*)(ws + 7864320);   // 256*320 bf16 = 160 KB

  kA<<<dim3(N_TOT/64 + 10), dim3(256), 0, stream>>>(x, Ws, bs, Wh, bh, Wo,
                                                    sBuf, sfrag, hBuf, (unsigned int*)WoT);
  kB<<<dim3(N_TOT/32), dim3(256), 0, stream>>>(sBuf, sfrag, hBuf, Umini);
  kC<<<dim3(N_TOT/64), dim3(256), 0, stream>>>(Umini, WoT, bo, x, gamma, beta, out);
}